// Round 6
// baseline (381.380 us; speedup 1.0000x reference)
//
#include <hip/hip_runtime.h>
#include <hip/hip_bf16.h>

// Problem constants (static graph layout from the reference)
#define NG 128          // graphs
#define NPG 1024        // nodes per graph
#define NN (NG * NPG)   // 131072 nodes
#define NE (NN * 32)    // 4194304 edges
#define CH 256          // channels
#define KSEL 512        // top-k per graph

// Output layout (all float32, concatenated flat in return order)
#define OUT_X      0
#define OUT_EDGE   16777216   // 65536*256
#define OUT_BATCH  25165824   // + 2*4194304
#define OUT_PERM   25231360
#define OUT_SCORES 25296896
// total 25362432 floats

// Workspace layout (bytes)
#define WS_SCORES  0           // 131072 floats = 524288 B
#define WS_KEEP    524288      // bit-packed: 131072 bits = 16384 B (L1-resident)
#define WS_COUNTS  540672      // 1024 ints
#define WS_OFFSETS 544768      // 1024 ints

// ---------------- Kernel 1: scores = tanh(x@W1 + b1) @ W2 + b2 ----------------
// R3 was LDS-PIPE-bound: 48 ds_read_b128/chunk/wave x 12cyc x 4 waves = 2304
// cyc/CU vs 1024 VALU cyc/SIMD (model matched measured 245us exactly).
// Fix: x[n][k] is wave-uniform (lanes own columns) -> load X via SCALAR loads
// (readfirstlane-forced uniform address -> s_load_dwordx4, K$) and feed FMA as
// the one allowed SGPR operand. Deletes all 32 X broadcast ds_reads/chunk/wave;
// DS drops to 768 cyc/CU < VALU 1024 cyc/SIMD -> VALU-bound.
// LDS: single-buffer W1 chunk [16][256] = 16 KiB. Occupancy (not explicit dbuf)
// hides the staging drain (m114 wave-level overlap; R4/R5 dbuf cost VGPRs).
__global__ __launch_bounds__(256, 6)
void k_scores(const float* __restrict__ x, const float* __restrict__ W1,
              const float* __restrict__ b1, const float* __restrict__ W2,
              const float* __restrict__ b2, float* __restrict__ scores)
{
    __shared__ __align__(16) float W1s[16][CH];  // 16 KiB

    const int tid = threadIdx.x;
    const int w_  = tid >> 6;
    const int l   = tid & 63;
    const int wq  = __builtin_amdgcn_readfirstlane(w_);   // provably wave-uniform
    const int n0  = blockIdx.x * 32;

    // this wave's 8 node rows (uniform base -> scalar loads)
    const float* xw = x + (size_t)(n0 + wq * 8) * CH;

    const float4 b1v = *(const float4*)&b1[l * 4];
    float acc[8][4];
    #pragma unroll
    for (int n = 0; n < 8; ++n) {
        acc[n][0] = b1v.x; acc[n][1] = b1v.y; acc[n][2] = b1v.z; acc[n][3] = b1v.w;
    }

    float4 sxA[8], sxB[8];

    for (int kc = 0; kc < 16; ++kc) {
        __syncthreads();   // previous chunk's compute done before overwrite

        // stage W1 chunk (16 rows x 256 cols = 16 KiB) via global_load_lds:
        // wave-uniform LDS base + lane*16, 4 loads per wave
        #pragma unroll
        for (int it = 0; it < 4; ++it) {
            const float* g = W1 + (size_t)kc * (16 * CH) + (w_ * 4 + it) * CH + l * 4;
            float* lb = &W1s[0][0] + (w_ * 4 + it) * CH;
            __builtin_amdgcn_global_load_lds(
                (const __attribute__((address_space(1))) void*)g,
                (__attribute__((address_space(3))) void*)lb, 16, 0, 0);
        }

        // prefetch kq=0 X (scalar, in flight during the staging drain)
        #pragma unroll
        for (int n = 0; n < 8; ++n)
            sxA[n] = *(const float4*)(xw + (size_t)n * CH + kc * 16);

        __syncthreads();   // staging drain

        #pragma unroll
        for (int kq = 0; kq < 4; ++kq) {
            const int k4 = kq * 4;
            // prefetch next kq's X while computing this one (alternating regs)
            if (kq < 3) {
                if ((kq & 1) == 0) {
                    #pragma unroll
                    for (int n = 0; n < 8; ++n)
                        sxB[n] = *(const float4*)(xw + (size_t)n * CH + kc * 16 + k4 + 4);
                } else {
                    #pragma unroll
                    for (int n = 0; n < 8; ++n)
                        sxA[n] = *(const float4*)(xw + (size_t)n * CH + kc * 16 + k4 + 4);
                }
            }
            const float4 wv0 = *(const float4*)&W1s[k4 + 0][l * 4];
            const float4 wv1 = *(const float4*)&W1s[k4 + 1][l * 4];
            const float4 wv2 = *(const float4*)&W1s[k4 + 2][l * 4];
            const float4 wv3 = *(const float4*)&W1s[k4 + 3][l * 4];
            #pragma unroll
            for (int n = 0; n < 8; ++n) {
                const float4 xv = ((kq & 1) == 0) ? sxA[n] : sxB[n];
                acc[n][0] = fmaf(xv.x, wv0.x, acc[n][0]);
                acc[n][1] = fmaf(xv.x, wv0.y, acc[n][1]);
                acc[n][2] = fmaf(xv.x, wv0.z, acc[n][2]);
                acc[n][3] = fmaf(xv.x, wv0.w, acc[n][3]);
                acc[n][0] = fmaf(xv.y, wv1.x, acc[n][0]);
                acc[n][1] = fmaf(xv.y, wv1.y, acc[n][1]);
                acc[n][2] = fmaf(xv.y, wv1.z, acc[n][2]);
                acc[n][3] = fmaf(xv.y, wv1.w, acc[n][3]);
                acc[n][0] = fmaf(xv.z, wv2.x, acc[n][0]);
                acc[n][1] = fmaf(xv.z, wv2.y, acc[n][1]);
                acc[n][2] = fmaf(xv.z, wv2.z, acc[n][2]);
                acc[n][3] = fmaf(xv.z, wv2.w, acc[n][3]);
                acc[n][0] = fmaf(xv.w, wv3.x, acc[n][0]);
                acc[n][1] = fmaf(xv.w, wv3.y, acc[n][1]);
                acc[n][2] = fmaf(xv.w, wv3.z, acc[n][2]);
                acc[n][3] = fmaf(xv.w, wv3.w, acc[n][3]);
            }
        }
    }

    // epilogue: tanh, dot with W2 slice, 64-lane reduce per node
    const float4 w2v = *(const float4*)&W2[l * 4];
    const float  bb  = b2[0];
    float s_[8];
    #pragma unroll
    for (int n = 0; n < 8; ++n) {
        s_[n] = tanhf(acc[n][0]) * w2v.x + tanhf(acc[n][1]) * w2v.y
              + tanhf(acc[n][2]) * w2v.z + tanhf(acc[n][3]) * w2v.w;
    }
    #pragma unroll
    for (int off = 1; off < 64; off <<= 1)
        #pragma unroll
        for (int n = 0; n < 8; ++n)
            s_[n] += __shfl_xor(s_[n], off, 64);

    if (l == 0) {
        #pragma unroll
        for (int n = 0; n < 8; ++n)
            scores[n0 + w_ * 8 + n] = s_[n] + bb;
    }
}

// ---------------- Kernel 2: per-graph bitonic top-k (full sort of 1024) -------
__global__ __launch_bounds__(512)
void k_topk(const float* __restrict__ scores, float* __restrict__ out,
            unsigned int* __restrict__ keep_bits)
{
    __shared__ float sv[1024];
    __shared__ int   si[1024];
    const int g = blockIdx.x;
    const int t = threadIdx.x;
    sv[t]       = scores[g * NPG + t];       si[t]       = t;
    sv[t + 512] = scores[g * NPG + t + 512]; si[t + 512] = t + 512;

    for (int size = 2; size <= 1024; size <<= 1) {
        for (int stride = size >> 1; stride > 0; stride >>= 1) {
            __syncthreads();
            const int lo = ((t & ~(stride - 1)) << 1) | (t & (stride - 1));
            const int hi = lo + stride;
            const bool dirDesc = ((lo & size) == 0);
            const float va = sv[lo], vb = sv[hi];
            const int ia = si[lo], ib = si[hi];
            const bool aB = (va > vb) || (va == vb && ia < ib);
            if (aB != dirDesc) {
                sv[lo] = vb; sv[hi] = va;
                si[lo] = ib; si[hi] = ia;
            }
        }
    }
    __syncthreads();
    // rank t of this graph survives (t in [0,512))
    const int gi = g * NPG + si[t];
    out[OUT_PERM   + g * KSEL + t] = (float)gi;
    out[OUT_SCORES + g * KSEL + t] = sv[t];
    out[OUT_BATCH  + g * KSEL + t] = (float)g;
    atomicOr(&keep_bits[gi >> 5], 1u << (gi & 31));
}

// ---------------- Kernel 3: gather x_pooled ----------------
__global__ __launch_bounds__(256)
void k_gather(const float* __restrict__ x, const float* __restrict__ perm_f,
              float* __restrict__ out_x)
{
    const int row  = blockIdx.x * 4 + (threadIdx.x >> 6);
    const int lane = threadIdx.x & 63;
    const int pi = (int)perm_f[row];
    const float4* src = (const float4*)&x[(size_t)pi * CH];
    float4* dst = (float4*)&out_x[(size_t)row * CH];
    dst[lane] = src[lane];
}

// ---------------- Kernel 4: fill edge output with -1 ----------------
__global__ __launch_bounds__(256)
void k_fill(float* __restrict__ out_edge)
{
    const int i = blockIdx.x * blockDim.x + threadIdx.x;
    ((float4*)out_edge)[i] = make_float4(-1.f, -1.f, -1.f, -1.f);
}

// ---------------- Kernel 5: per-block kept-edge counts ----------------
__global__ __launch_bounds__(256)
void k_edgecount(const int* __restrict__ ei, const unsigned int* __restrict__ keep_bits,
                 int* __restrict__ counts)
{
    const int t = threadIdx.x;
    const size_t base = (size_t)blockIdx.x * 4096 + (size_t)t * 16;
    const int* rowp = ei;
    const int* colp = ei + NE;
    int rv[16], cv[16];
    #pragma unroll
    for (int q = 0; q < 4; ++q) {
        int4 r4 = *(const int4*)&rowp[base + q * 4];
        int4 c4 = *(const int4*)&colp[base + q * 4];
        rv[q*4+0]=r4.x; rv[q*4+1]=r4.y; rv[q*4+2]=r4.z; rv[q*4+3]=r4.w;
        cv[q*4+0]=c4.x; cv[q*4+1]=c4.y; cv[q*4+2]=c4.z; cv[q*4+3]=c4.w;
    }
    int cnt = 0;
    #pragma unroll
    for (int q = 0; q < 16; ++q)
        cnt += (int)((keep_bits[rv[q] >> 5] >> (rv[q] & 31)) &
                     (keep_bits[cv[q] >> 5] >> (cv[q] & 31)) & 1u);

    #pragma unroll
    for (int off = 1; off < 64; off <<= 1) cnt += __shfl_xor(cnt, off, 64);
    __shared__ int wsum[4];
    if ((t & 63) == 0) wsum[t >> 6] = cnt;
    __syncthreads();
    if (t == 0) counts[blockIdx.x] = wsum[0] + wsum[1] + wsum[2] + wsum[3];
}

// ---------------- Kernel 6: exclusive scan of 1024 block counts ----------------
__global__ __launch_bounds__(1024)
void k_scan(const int* __restrict__ counts, int* __restrict__ offsets)
{
    __shared__ int tmp[1024];
    const int t = threadIdx.x;
    const int c = counts[t];
    tmp[t] = c;
    __syncthreads();
    for (int off = 1; off < 1024; off <<= 1) {
        int v = (t >= off) ? tmp[t - off] : 0;
        __syncthreads();
        tmp[t] += v;
        __syncthreads();
    }
    offsets[t] = tmp[t] - c;
}

// ---------------- Kernel 7: stable scatter of kept edges ----------------
__global__ __launch_bounds__(256)
void k_scatter(const int* __restrict__ ei, const unsigned int* __restrict__ keep_bits,
               const int* __restrict__ offsets, float* __restrict__ out_edge)
{
    const int t = threadIdx.x;
    const size_t base = (size_t)blockIdx.x * 4096 + (size_t)t * 16;
    const int* rowp = ei;
    const int* colp = ei + NE;
    int rv[16], cv[16];
    #pragma unroll
    for (int q = 0; q < 4; ++q) {
        int4 r4 = *(const int4*)&rowp[base + q * 4];
        int4 c4 = *(const int4*)&colp[base + q * 4];
        rv[q*4+0]=r4.x; rv[q*4+1]=r4.y; rv[q*4+2]=r4.z; rv[q*4+3]=r4.w;
        cv[q*4+0]=c4.x; cv[q*4+1]=c4.y; cv[q*4+2]=c4.z; cv[q*4+3]=c4.w;
    }
    unsigned m = 0; int cnt = 0;
    #pragma unroll
    for (int q = 0; q < 16; ++q) {
        const bool kk = ((keep_bits[rv[q] >> 5] >> (rv[q] & 31)) &
                         (keep_bits[cv[q] >> 5] >> (cv[q] & 31)) & 1u) != 0u;
        m |= ((unsigned)kk) << q;
        cnt += (int)kk;
    }
    // exclusive scan over the block's 256 threads (thread chunks are contiguous
    // in edge order, so this preserves the stable original ordering)
    const int lane = t & 63, w = t >> 6;
    int incl = cnt;
    #pragma unroll
    for (int off = 1; off < 64; off <<= 1) {
        int v = __shfl_up(incl, off, 64);
        if (lane >= off) incl += v;
    }
    __shared__ int wtot[4];
    if (lane == 63) wtot[w] = incl;
    __syncthreads();
    int wbase = 0;
    for (int i = 0; i < w; ++i) wbase += wtot[i];
    int pos = offsets[blockIdx.x] + wbase + (incl - cnt);
    #pragma unroll
    for (int q = 0; q < 16; ++q) {
        if (m & (1u << q)) {
            out_edge[pos]      = (float)rv[q];
            out_edge[NE + pos] = (float)cv[q];
            ++pos;
        }
    }
}

extern "C" void kernel_launch(void* const* d_in, const int* in_sizes, int n_in,
                              void* d_out, int out_size, void* d_ws, size_t ws_size,
                              hipStream_t stream)
{
    const float* x  = (const float*)d_in[0];
    const int*   ei = (const int*)d_in[1];
    // d_in[2] (batch) is implied by the static layout; unused
    const float* W1 = (const float*)d_in[3];
    const float* b1 = (const float*)d_in[4];
    const float* W2 = (const float*)d_in[5];
    const float* b2 = (const float*)d_in[6];

    float* out = (float*)d_out;
    char*  ws  = (char*)d_ws;
    float*        scores    = (float*)(ws + WS_SCORES);
    unsigned int* keep_bits = (unsigned int*)(ws + WS_KEEP);
    int*          counts    = (int*)(ws + WS_COUNTS);
    int*          offsets   = (int*)(ws + WS_OFFSETS);

    hipMemsetAsync(keep_bits, 0, NN / 8, stream);

    k_scores<<<NN / 32, 256, 0, stream>>>(x, W1, b1, W2, b2, scores);
    k_topk<<<NG, 512, 0, stream>>>(scores, out, keep_bits);
    k_gather<<<(NG * KSEL) / 4, 256, 0, stream>>>(x, out + OUT_PERM, out + OUT_X);
    k_fill<<<(2 * NE) / (4 * 256), 256, 0, stream>>>(out + OUT_EDGE);
    k_edgecount<<<NE / 4096, 256, 0, stream>>>(ei, keep_bits, counts);
    k_scan<<<1, 1024, 0, stream>>>(counts, offsets);
    k_scatter<<<NE / 4096, 256, 0, stream>>>(ei, keep_bits, offsets, out + OUT_EDGE);
}

// Round 7
// 178.685 us; speedup vs baseline: 2.1344x; 2.1344x over previous
//
#include <hip/hip_runtime.h>
#include <hip/hip_bf16.h>

// Problem constants (static graph layout from the reference)
#define NG 128          // graphs
#define NPG 1024        // nodes per graph
#define NN (NG * NPG)   // 131072 nodes
#define NE (NN * 32)    // 4194304 edges
#define CH 256          // channels
#define KSEL 512        // top-k per graph

#define CAP 128         // band capacity per graph
#define EPS 0.02f       // bf16-score uncertainty band half-width (~100 sigma)

// Output layout (all float32, concatenated flat in return order)
#define OUT_X      0
#define OUT_EDGE   16777216
#define OUT_BATCH  25165824
#define OUT_PERM   25231360
#define OUT_SCORES 25296896

// Workspace layout (bytes)
#define WS_SCORES  0           // 131072 f32
#define WS_KEEP    524288      // bit-packed keep: 16 KB
#define WS_COUNTS  540672      // 1024 int
#define WS_OFFSETS 544768      // 1024 int
#define WS_BFRAG   548864      // W1 bf16 fragment-linear: 128 KB
#define WS_BIDX    679936      // band local idx: NG*CAP int = 64 KB
#define WS_BSCORE  745472      // band fp32 scores: 64 KB
#define WS_BN      811008      // band_n: NG int
#define WS_BLO     811520      // band_lo: NG int

typedef __attribute__((ext_vector_type(8))) short bf16x8;
typedef __attribute__((ext_vector_type(4))) float f32x4;

__device__ __forceinline__ unsigned short f2bf(float f) {
    unsigned int b = __float_as_uint(f);
    return (unsigned short)((b + 0x7fffu + ((b >> 16) & 1u)) >> 16);  // RNE
}

// ---------- Kernel 0: pack W1 (fp32 [k][col]) -> bf16 fragment-linear ----------
// frag chunk (s, n): 1 KB; lane l, elem j holds W1[s*32 + (l>>4)*8 + j][n*16 + (l&15)]
__global__ __launch_bounds__(256)
void k_cvtW(const float* __restrict__ W1, unsigned short* __restrict__ W1b)
{
    const int t = blockIdx.x * 256 + threadIdx.x;   // 0..8191
    const int s    = t >> 10;
    const int rem  = t & 1023;
    const int n    = rem >> 6;
    const int lane = rem & 63;
    const int kbase = s * 32 + (lane >> 4) * 8;
    const int col   = n * 16 + (lane & 15);
    unsigned short u[8];
    #pragma unroll
    for (int j = 0; j < 8; ++j)
        u[j] = f2bf(W1[(size_t)(kbase + j) * CH + col]);
    unsigned int w0 = u[0] | ((unsigned int)u[1] << 16);
    unsigned int w1 = u[2] | ((unsigned int)u[3] << 16);
    unsigned int w2 = u[4] | ((unsigned int)u[5] << 16);
    unsigned int w3 = u[6] | ((unsigned int)u[7] << 16);
    uint4 v; v.x = w0; v.y = w1; v.z = w2; v.w = w3;
    *(uint4*)&W1b[(size_t)t * 8] = v;
}

// ---------- Kernel 1: approx scores via bf16 MFMA ----------
// Block: 256 thr (4 waves), 32 nodes. Wave w_: cols [64w_, 64w_+64) (4 N-tiles),
// both 16-row M-subtiles. A (x tile) staged once in LDS in fragment-linear bf16.
// B (W1) frags read from W1b (L2-hot). Epilogue: +b1, tanh, dot W2, reduce.
__global__ __launch_bounds__(256)
void k_mfma_scores(const float* __restrict__ x, const unsigned short* __restrict__ W1b,
                   const float* __restrict__ b1, const float* __restrict__ W2,
                   const float* __restrict__ b2, float* __restrict__ scores)
{
    __shared__ short As[8192];       // 32 rows x 256 k bf16, fragment-linear, 16 KB
    __shared__ float epi[4][32];

    const int tid = threadIdx.x;
    const int w_  = tid >> 6;
    const int l   = tid & 63;
    const int n0  = blockIdx.x * 32;

    // ---- stage x tile: fp32 coalesced read -> bf16 fragment-linear LDS ----
    // frag short idx for (row, k): msub*4096 + s*512 + g*128 + (row&15)*8 + (k&7)
    #pragma unroll
    for (int it = 0; it < 8; ++it) {
        const int flat = it * 1024 + tid * 4;
        const int row = flat >> 8;
        const int c   = flat & 255;            // multiple of 4
        const float4 v = *(const float4*)&x[(size_t)(n0 + row) * CH + c];
        const int msub = row >> 4, r16 = row & 15;
        const int s = c >> 5, ksub = c & 31, g = ksub >> 3, j = ksub & 7; // j in {0,4}
        const int idx = msub * 4096 + s * 512 + g * 128 + r16 * 8 + j;
        uint2 p;
        p.x = f2bf(v.x) | ((unsigned int)f2bf(v.y) << 16);
        p.y = f2bf(v.z) | ((unsigned int)f2bf(v.w) << 16);
        *(uint2*)&As[idx] = p;
    }
    __syncthreads();

    f32x4 acc[2][4];
    #pragma unroll
    for (int m = 0; m < 2; ++m)
        #pragma unroll
        for (int n = 0; n < 4; ++n)
            acc[m][n] = (f32x4){0.f, 0.f, 0.f, 0.f};

    #pragma unroll
    for (int s = 0; s < 8; ++s) {
        const bf16x8 a0 = *(const bf16x8*)&As[0 * 4096 + s * 512 + l * 8];
        const bf16x8 a1 = *(const bf16x8*)&As[1 * 4096 + s * 512 + l * 8];
        #pragma unroll
        for (int ni = 0; ni < 4; ++ni) {
            const int nt = w_ * 4 + ni;
            const bf16x8 b = *(const bf16x8*)&W1b[(size_t)(s * 16 + nt) * 512 + l * 8];
            acc[0][ni] = __builtin_amdgcn_mfma_f32_16x16x32_bf16(a0, b, acc[0][ni], 0, 0, 0);
            acc[1][ni] = __builtin_amdgcn_mfma_f32_16x16x32_bf16(a1, b, acc[1][ni], 0, 0, 0);
        }
    }

    // ---- epilogue: h = acc + b1[col]; t = tanh(h); partial row sums of t*W2 ----
    float part[8];   // [msub*4 + reg], rows msub*16 + (l>>4)*4 + reg over this wave's 64 cols
    #pragma unroll
    for (int i = 0; i < 8; ++i) part[i] = 0.f;
    #pragma unroll
    for (int ni = 0; ni < 4; ++ni) {
        const int col = w_ * 64 + ni * 16 + (l & 15);
        const float b1c = b1[col];
        const float w2c = W2[col];
        #pragma unroll
        for (int m = 0; m < 2; ++m)
            #pragma unroll
            for (int r = 0; r < 4; ++r)
                part[m * 4 + r] += tanhf(acc[m][ni][r] + b1c) * w2c;
    }
    #pragma unroll
    for (int off = 1; off < 16; off <<= 1)
        #pragma unroll
        for (int i = 0; i < 8; ++i)
            part[i] += __shfl_xor(part[i], off, 64);

    if ((l & 15) == 0) {
        const int gq = l >> 4;
        #pragma unroll
        for (int m = 0; m < 2; ++m)
            #pragma unroll
            for (int r = 0; r < 4; ++r)
                epi[w_][m * 16 + gq * 4 + r] = part[m * 4 + r];
    }
    __syncthreads();
    if (tid < 32)
        scores[n0 + tid] = epi[0][tid] + epi[1][tid] + epi[2][tid] + epi[3][tid] + b2[0];
}

// ---------- Kernel 2: per-graph bitonic sort + certain-keep + band extraction ----------
__global__ __launch_bounds__(512)
void k_topk(const float* __restrict__ scores, float* __restrict__ out,
            unsigned int* __restrict__ keep_bits, int* __restrict__ band_idx,
            int* __restrict__ band_n, int* __restrict__ band_lo)
{
    __shared__ float sv[1024];
    __shared__ int   si[1024];
    __shared__ int   s_lo, s_hi;
    const int g = blockIdx.x;
    const int t = threadIdx.x;
    sv[t]       = scores[g * NPG + t];       si[t]       = t;
    sv[t + 512] = scores[g * NPG + t + 512]; si[t + 512] = t + 512;

    for (int size = 2; size <= 1024; size <<= 1) {
        for (int stride = size >> 1; stride > 0; stride >>= 1) {
            __syncthreads();
            const int lo = ((t & ~(stride - 1)) << 1) | (t & (stride - 1));
            const int hi = lo + stride;
            const bool dirDesc = ((lo & size) == 0);
            const float va = sv[lo], vb = sv[hi];
            const int ia = si[lo], ib = si[hi];
            const bool aB = (va > vb) || (va == vb && ia < ib);
            if (aB != dirDesc) {
                sv[lo] = vb; sv[hi] = va;
                si[lo] = ib; si[hi] = ia;
            }
        }
    }
    __syncthreads();
    if (t == 0) { s_hi = 1024; }
    __syncthreads();
    const float tau = sv[511];
    // lo: first rank with sv <= tau+EPS (exists; sorted desc => unique boundary)
    if (sv[t] <= tau + EPS && (t == 0 || sv[t - 1] > tau + EPS)) s_lo = t;
    // hi: first rank >= 512 with sv < tau-EPS
    {
        const int p2 = t + 512;
        if (sv[p2] < tau - EPS && sv[p2 - 1] >= tau - EPS) s_hi = p2;
    }
    __syncthreads();
    const int lo = s_lo;
    const int bn = min(s_hi - lo, CAP);

    // certain keeps: ranks [0, lo)
    const int gi = g * NPG + si[t];
    out[OUT_BATCH + g * KSEL + t] = (float)g;
    if (t < lo) {
        out[OUT_PERM   + g * KSEL + t] = (float)gi;
        out[OUT_SCORES + g * KSEL + t] = sv[t];
        atomicOr(&keep_bits[gi >> 5], 1u << (gi & 31));
    }
    // band slots
    if (t < CAP)
        band_idx[g * CAP + t] = (t < bn) ? si[lo + t] : 0;
    if (t == 0) { band_n[g] = bn; band_lo[g] = lo; }
}

// ---------- Kernel 3: exact fp32 rescore of band nodes (R3 structure + indirection) ----------
__global__ __launch_bounds__(256, 2)
void k_rescore(const float* __restrict__ x, const float* __restrict__ W1,
               const float* __restrict__ b1, const float* __restrict__ W2,
               const float* __restrict__ b2, const int* __restrict__ band_idx,
               const int* __restrict__ band_n, float* __restrict__ band_scores)
{
    const int g = blockIdx.x >> 2;
    const int c0 = (blockIdx.x & 3) * 32;
    if (band_n[g] <= c0) return;   // uniform early-exit (no barriers crossed)

    __shared__ __align__(16) float W1s[16][CH];
    __shared__ __align__(16) float Xs[32][16];

    const int tid = threadIdx.x;
    const int w_  = tid >> 6;
    const int l   = tid & 63;

    int iv = 0;
    if (w_ < 2) iv = band_idx[g * CAP + c0 + w_ * 16 + (l >> 2)] & 1023;
    const float* xg = x + ((size_t)g * NPG + iv) * CH;

    const float4 b1v = *(const float4*)&b1[l * 4];
    float acc[8][4];
    #pragma unroll
    for (int n = 0; n < 8; ++n) {
        acc[n][0] = b1v.x; acc[n][1] = b1v.y; acc[n][2] = b1v.z; acc[n][3] = b1v.w;
    }

    for (int kc = 0; kc < 16; ++kc) {
        __syncthreads();
        #pragma unroll
        for (int it = 0; it < 4; ++it) {
            const float* gp = W1 + (size_t)kc * (16 * CH) + (w_ * 4 + it) * CH + l * 4;
            float* lb = &W1s[0][0] + (w_ * 4 + it) * CH;
            __builtin_amdgcn_global_load_lds(
                (const __attribute__((address_space(1))) void*)gp,
                (__attribute__((address_space(3))) void*)lb, 16, 0, 0);
        }
        if (w_ < 2) {
            const float* gp = xg + kc * 16 + (l & 3) * 4;
            float* lb = &Xs[0][0] + w_ * 256;
            __builtin_amdgcn_global_load_lds(
                (const __attribute__((address_space(1))) void*)gp,
                (__attribute__((address_space(3))) void*)lb, 16, 0, 0);
        }
        __syncthreads();

        #pragma unroll
        for (int kq = 0; kq < 4; ++kq) {
            const int k4 = kq * 4;
            const float4 wv0 = *(const float4*)&W1s[k4 + 0][l * 4];
            const float4 wv1 = *(const float4*)&W1s[k4 + 1][l * 4];
            const float4 wv2 = *(const float4*)&W1s[k4 + 2][l * 4];
            const float4 wv3 = *(const float4*)&W1s[k4 + 3][l * 4];
            #pragma unroll
            for (int n = 0; n < 8; ++n) {
                const float4 xv = *(const float4*)&Xs[w_ * 8 + n][k4];
                acc[n][0] = fmaf(xv.x, wv0.x, acc[n][0]);
                acc[n][1] = fmaf(xv.x, wv0.y, acc[n][1]);
                acc[n][2] = fmaf(xv.x, wv0.z, acc[n][2]);
                acc[n][3] = fmaf(xv.x, wv0.w, acc[n][3]);
                acc[n][0] = fmaf(xv.y, wv1.x, acc[n][0]);
                acc[n][1] = fmaf(xv.y, wv1.y, acc[n][1]);
                acc[n][2] = fmaf(xv.y, wv1.z, acc[n][2]);
                acc[n][3] = fmaf(xv.y, wv1.w, acc[n][3]);
                acc[n][0] = fmaf(xv.z, wv2.x, acc[n][0]);
                acc[n][1] = fmaf(xv.z, wv2.y, acc[n][1]);
                acc[n][2] = fmaf(xv.z, wv2.z, acc[n][2]);
                acc[n][3] = fmaf(xv.z, wv2.w, acc[n][3]);
                acc[n][0] = fmaf(xv.w, wv3.x, acc[n][0]);
                acc[n][1] = fmaf(xv.w, wv3.y, acc[n][1]);
                acc[n][2] = fmaf(xv.w, wv3.z, acc[n][2]);
                acc[n][3] = fmaf(xv.w, wv3.w, acc[n][3]);
            }
        }
    }

    const float4 w2v = *(const float4*)&W2[l * 4];
    const float  bb  = b2[0];
    float s_[8];
    #pragma unroll
    for (int n = 0; n < 8; ++n) {
        s_[n] = tanhf(acc[n][0]) * w2v.x + tanhf(acc[n][1]) * w2v.y
              + tanhf(acc[n][2]) * w2v.z + tanhf(acc[n][3]) * w2v.w;
    }
    #pragma unroll
    for (int off = 1; off < 64; off <<= 1)
        #pragma unroll
        for (int n = 0; n < 8; ++n)
            s_[n] += __shfl_xor(s_[n], off, 64);

    if (l == 0) {
        #pragma unroll
        for (int n = 0; n < 8; ++n)
            band_scores[g * CAP + c0 + w_ * 8 + n] = s_[n] + bb;
    }
}

// ---------- Kernel 4: select top-(512-lo) of band by fp32 score ----------
__global__ __launch_bounds__(64)
void k_bandsel(const float* __restrict__ band_scores, const int* __restrict__ band_idx,
               const int* __restrict__ band_n, const int* __restrict__ band_lo,
               float* __restrict__ out, unsigned int* __restrict__ keep_bits)
{
    __shared__ float bs[CAP];
    __shared__ int   bi[CAP];
    const int g = blockIdx.x;
    const int t = threadIdx.x;
    const int n  = band_n[g];
    const int lo = band_lo[g];
    int needed = KSEL - lo;
    if (needed > n) needed = n;   // safety clamp (never expected)

    #pragma unroll
    for (int h = 0; h < 2; ++h) {
        const int q = t + h * 64;
        const bool valid = q < n;
        bs[q] = valid ? band_scores[g * CAP + q] : -3.402823466e+38f;
        bi[q] = valid ? band_idx[g * CAP + q] : (NPG + q);
    }
    __syncthreads();
    for (int size = 2; size <= CAP; size <<= 1) {
        for (int stride = size >> 1; stride > 0; stride >>= 1) {
            __syncthreads();
            const int lo_i = ((t & ~(stride - 1)) << 1) | (t & (stride - 1));
            const int hi_i = lo_i + stride;
            const bool dirDesc = ((lo_i & size) == 0);
            const float va = bs[lo_i], vb = bs[hi_i];
            const int ia = bi[lo_i], ib = bi[hi_i];
            const bool aB = (va > vb) || (va == vb && ia < ib);
            if (aB != dirDesc) {
                bs[lo_i] = vb; bs[hi_i] = va;
                bi[lo_i] = ib; bi[hi_i] = ia;
            }
        }
    }
    __syncthreads();
    #pragma unroll
    for (int h = 0; h < 2; ++h) {
        const int s = t + h * 64;
        if (s < needed) {
            const int li = bi[s];
            const int gi = g * NPG + li;
            out[OUT_PERM   + g * KSEL + lo + s] = (float)gi;
            out[OUT_SCORES + g * KSEL + lo + s] = bs[s];
            atomicOr(&keep_bits[gi >> 5], 1u << (gi & 31));
        }
    }
}

// ---------- Kernel 5: gather x_pooled ----------
__global__ __launch_bounds__(256)
void k_gather(const float* __restrict__ x, const float* __restrict__ perm_f,
              float* __restrict__ out_x)
{
    const int row  = blockIdx.x * 4 + (threadIdx.x >> 6);
    const int lane = threadIdx.x & 63;
    const int pi = (int)perm_f[row];
    const float4* src = (const float4*)&x[(size_t)pi * CH];
    float4* dst = (float4*)&out_x[(size_t)row * CH];
    dst[lane] = src[lane];
}

// ---------- Kernel 6: fill edge output with -1 ----------
__global__ __launch_bounds__(256)
void k_fill(float* __restrict__ out_edge)
{
    const int i = blockIdx.x * blockDim.x + threadIdx.x;
    ((float4*)out_edge)[i] = make_float4(-1.f, -1.f, -1.f, -1.f);
}

// ---------- Kernel 7: per-block kept-edge counts ----------
__global__ __launch_bounds__(256)
void k_edgecount(const int* __restrict__ ei, const unsigned int* __restrict__ keep_bits,
                 int* __restrict__ counts)
{
    const int t = threadIdx.x;
    const size_t base = (size_t)blockIdx.x * 4096 + (size_t)t * 16;
    const int* rowp = ei;
    const int* colp = ei + NE;
    int rv[16], cv[16];
    #pragma unroll
    for (int q = 0; q < 4; ++q) {
        int4 r4 = *(const int4*)&rowp[base + q * 4];
        int4 c4 = *(const int4*)&colp[base + q * 4];
        rv[q*4+0]=r4.x; rv[q*4+1]=r4.y; rv[q*4+2]=r4.z; rv[q*4+3]=r4.w;
        cv[q*4+0]=c4.x; cv[q*4+1]=c4.y; cv[q*4+2]=c4.z; cv[q*4+3]=c4.w;
    }
    int cnt = 0;
    #pragma unroll
    for (int q = 0; q < 16; ++q)
        cnt += (int)((keep_bits[rv[q] >> 5] >> (rv[q] & 31)) &
                     (keep_bits[cv[q] >> 5] >> (cv[q] & 31)) & 1u);

    #pragma unroll
    for (int off = 1; off < 64; off <<= 1) cnt += __shfl_xor(cnt, off, 64);
    __shared__ int wsum[4];
    if ((t & 63) == 0) wsum[t >> 6] = cnt;
    __syncthreads();
    if (t == 0) counts[blockIdx.x] = wsum[0] + wsum[1] + wsum[2] + wsum[3];
}

// ---------- Kernel 8: exclusive scan of 1024 block counts ----------
__global__ __launch_bounds__(1024)
void k_scan(const int* __restrict__ counts, int* __restrict__ offsets)
{
    __shared__ int tmp[1024];
    const int t = threadIdx.x;
    const int c = counts[t];
    tmp[t] = c;
    __syncthreads();
    for (int off = 1; off < 1024; off <<= 1) {
        int v = (t >= off) ? tmp[t - off] : 0;
        __syncthreads();
        tmp[t] += v;
        __syncthreads();
    }
    offsets[t] = tmp[t] - c;
}

// ---------- Kernel 9: stable scatter of kept edges ----------
__global__ __launch_bounds__(256)
void k_scatter(const int* __restrict__ ei, const unsigned int* __restrict__ keep_bits,
               const int* __restrict__ offsets, float* __restrict__ out_edge)
{
    const int t = threadIdx.x;
    const size_t base = (size_t)blockIdx.x * 4096 + (size_t)t * 16;
    const int* rowp = ei;
    const int* colp = ei + NE;
    int rv[16], cv[16];
    #pragma unroll
    for (int q = 0; q < 4; ++q) {
        int4 r4 = *(const int4*)&rowp[base + q * 4];
        int4 c4 = *(const int4*)&colp[base + q * 4];
        rv[q*4+0]=r4.x; rv[q*4+1]=r4.y; rv[q*4+2]=r4.z; rv[q*4+3]=r4.w;
        cv[q*4+0]=c4.x; cv[q*4+1]=c4.y; cv[q*4+2]=c4.z; cv[q*4+3]=c4.w;
    }
    unsigned m = 0; int cnt = 0;
    #pragma unroll
    for (int q = 0; q < 16; ++q) {
        const bool kk = ((keep_bits[rv[q] >> 5] >> (rv[q] & 31)) &
                         (keep_bits[cv[q] >> 5] >> (cv[q] & 31)) & 1u) != 0u;
        m |= ((unsigned)kk) << q;
        cnt += (int)kk;
    }
    const int lane = t & 63, w = t >> 6;
    int incl = cnt;
    #pragma unroll
    for (int off = 1; off < 64; off <<= 1) {
        int v = __shfl_up(incl, off, 64);
        if (lane >= off) incl += v;
    }
    __shared__ int wtot[4];
    if (lane == 63) wtot[w] = incl;
    __syncthreads();
    int wbase = 0;
    for (int i = 0; i < w; ++i) wbase += wtot[i];
    int pos = offsets[blockIdx.x] + wbase + (incl - cnt);
    #pragma unroll
    for (int q = 0; q < 16; ++q) {
        if (m & (1u << q)) {
            out_edge[pos]      = (float)rv[q];
            out_edge[NE + pos] = (float)cv[q];
            ++pos;
        }
    }
}

extern "C" void kernel_launch(void* const* d_in, const int* in_sizes, int n_in,
                              void* d_out, int out_size, void* d_ws, size_t ws_size,
                              hipStream_t stream)
{
    const float* x  = (const float*)d_in[0];
    const int*   ei = (const int*)d_in[1];
    const float* W1 = (const float*)d_in[3];
    const float* b1 = (const float*)d_in[4];
    const float* W2 = (const float*)d_in[5];
    const float* b2 = (const float*)d_in[6];

    float* out = (float*)d_out;
    char*  ws  = (char*)d_ws;
    float*          scores    = (float*)(ws + WS_SCORES);
    unsigned int*   keep_bits = (unsigned int*)(ws + WS_KEEP);
    int*            counts    = (int*)(ws + WS_COUNTS);
    int*            offsets   = (int*)(ws + WS_OFFSETS);
    unsigned short* W1b       = (unsigned short*)(ws + WS_BFRAG);
    int*            band_idx  = (int*)(ws + WS_BIDX);
    float*          band_sc   = (float*)(ws + WS_BSCORE);
    int*            band_n    = (int*)(ws + WS_BN);
    int*            band_lo   = (int*)(ws + WS_BLO);

    hipMemsetAsync(keep_bits, 0, NN / 8, stream);

    k_cvtW<<<32, 256, 0, stream>>>(W1, W1b);
    k_mfma_scores<<<NN / 32, 256, 0, stream>>>(x, W1b, b1, W2, b2, scores);
    k_topk<<<NG, 512, 0, stream>>>(scores, out, keep_bits, band_idx, band_n, band_lo);
    k_rescore<<<NG * (CAP / 32), 256, 0, stream>>>(x, W1, b1, W2, b2, band_idx, band_n, band_sc);
    k_bandsel<<<NG, 64, 0, stream>>>(band_sc, band_idx, band_n, band_lo, out, keep_bits);
    k_gather<<<(NG * KSEL) / 4, 256, 0, stream>>>(x, out + OUT_PERM, out + OUT_X);
    k_fill<<<(2 * NE) / (4 * 256), 256, 0, stream>>>(out + OUT_EDGE);
    k_edgecount<<<NE / 4096, 256, 0, stream>>>(ei, keep_bits, counts);
    k_scan<<<1, 1024, 0, stream>>>(counts, offsets);
    k_scatter<<<NE / 4096, 256, 0, stream>>>(ei, keep_bits, offsets, out + OUT_EDGE);
}

// Round 8
// 170.088 us; speedup vs baseline: 2.2422x; 1.0505x over previous
//
#include <hip/hip_runtime.h>
#include <hip/hip_bf16.h>

// Problem constants (static graph layout from the reference)
#define NG 128          // graphs
#define NPG 1024        // nodes per graph
#define NN (NG * NPG)   // 131072 nodes
#define NE (NN * 32)    // 4194304 edges
#define CH 256          // channels
#define KSEL 512        // top-k per graph

#define CAP 128         // band capacity per graph
#define EPS 0.02f       // bf16-score uncertainty band half-width (~100 sigma)

// Output layout (all float32, concatenated flat in return order)
#define OUT_X      0
#define OUT_EDGE   16777216
#define OUT_BATCH  25165824
#define OUT_PERM   25231360
#define OUT_SCORES 25296896

// Workspace layout (bytes)
#define WS_SCORES  0           // 131072 f32
#define WS_KEEP    524288      // bit-packed keep: 16 KB
#define WS_COUNTS  540672      // 1024 int
#define WS_OFFSETS 544768      // 1024 int
#define WS_BFRAG   548864      // W1 bf16 fragment-linear: 128 KB
#define WS_BIDX    679936      // band local idx: NG*CAP int = 64 KB
#define WS_BSCORE  745472      // band fp32 scores: 64 KB
#define WS_BN      811008      // band_n: NG int
#define WS_BLO     811520      // band_lo: NG int

typedef __attribute__((ext_vector_type(8))) short bf16x8;
typedef __attribute__((ext_vector_type(4))) float f32x4;

__device__ __forceinline__ unsigned short f2bf(float f) {
    unsigned int b = __float_as_uint(f);
    return (unsigned short)((b + 0x7fffu + ((b >> 16) & 1u)) >> 16);  // RNE
}

// fast tanh for the APPROX path only: 1 - 2/(exp(2h)+1).
// Saturates to +-1 for large |h| (exp->inf or ->0), no NaN. err ~1e-6 << EPS.
__device__ __forceinline__ float tanh_fast(float h) {
    const float e = __expf(2.0f * h);
    return 1.0f - 2.0f / (e + 1.0f);
}

// ---------- Kernel 0: pack W1 (fp32 [k][col]) -> bf16 fragment-linear ----------
// frag chunk (s, n): 1 KB; lane l, elem j holds W1[s*32 + (l>>4)*8 + j][n*16 + (l&15)]
__global__ __launch_bounds__(256)
void k_cvtW(const float* __restrict__ W1, unsigned short* __restrict__ W1b)
{
    const int t = blockIdx.x * 256 + threadIdx.x;   // 0..8191
    const int s    = t >> 10;
    const int rem  = t & 1023;
    const int n    = rem >> 6;
    const int lane = rem & 63;
    const int kbase = s * 32 + (lane >> 4) * 8;
    const int col   = n * 16 + (lane & 15);
    unsigned short u[8];
    #pragma unroll
    for (int j = 0; j < 8; ++j)
        u[j] = f2bf(W1[(size_t)(kbase + j) * CH + col]);
    uint4 v;
    v.x = u[0] | ((unsigned int)u[1] << 16);
    v.y = u[2] | ((unsigned int)u[3] << 16);
    v.z = u[4] | ((unsigned int)u[5] << 16);
    v.w = u[6] | ((unsigned int)u[7] << 16);
    *(uint4*)&W1b[(size_t)t * 8] = v;
}

// ---------- Kernel 1: approx scores via bf16 MFMA (v2) ----------
// Block: 256 thr (4 waves), 64 nodes (M=64: 4 msubs). Wave w_: cols [64w_,64w_+64).
// x tile in LDS: ROW-MAJOR bf16 [64][256] with T2 XOR swizzle (byte ^= (row&7)<<4):
//   staging writes linear/conflict-free; A-frag reads spread 8-way (R7's
//   fragment-linear layout had 16-way-conflicted staging writes: 3.67M cycles).
// B-frags double-buffered in regs (compile-time indices) -> L2 latency hidden.
__global__ __launch_bounds__(256, 3)
void k_mfma_scores(const float* __restrict__ x, const unsigned short* __restrict__ W1b,
                   const float* __restrict__ b1, const float* __restrict__ W2,
                   const float* __restrict__ b2, float* __restrict__ scores)
{
    __shared__ __align__(16) short As[64 * 256];   // 32 KB row-major bf16, swizzled
    __shared__ float epi[4][64];

    const int tid = threadIdx.x;
    const int w_  = tid >> 6;
    const int l   = tid & 63;
    const int n0  = blockIdx.x * 64;

    // ---- stage x tile: fp32 coalesced read -> bf16 row-major LDS (swizzled) ----
    #pragma unroll
    for (int it = 0; it < 16; ++it) {
        const int flat = it * 1024 + tid * 4;
        const int row = flat >> 8;
        const int c   = flat & 255;            // multiple of 4
        const float4 v = *(const float4*)&x[(size_t)(n0 + row) * CH + c];
        uint2 p;
        p.x = f2bf(v.x) | ((unsigned int)f2bf(v.y) << 16);
        p.y = f2bf(v.z) | ((unsigned int)f2bf(v.w) << 16);
        const int byte = (row * 512 + c * 2) ^ ((row & 7) << 4);
        *(uint2*)((char*)As + byte) = p;
    }
    __syncthreads();

    f32x4 acc[4][4];
    #pragma unroll
    for (int m = 0; m < 4; ++m)
        #pragma unroll
        for (int n = 0; n < 4; ++n)
            acc[m][n] = (f32x4){0.f, 0.f, 0.f, 0.f};

    // B-frag double buffer (all indices compile-time per unrolled iteration)
    const unsigned short* Wl = W1b + l * 8;
    bf16x8 bc[4], bn[4];
    #pragma unroll
    for (int ni = 0; ni < 4; ++ni)
        bc[ni] = *(const bf16x8*)&Wl[(size_t)(w_ * 4 + ni) * 512];

    #pragma unroll
    for (int s = 0; s < 8; ++s) {
        if (s < 7) {
            #pragma unroll
            for (int ni = 0; ni < 4; ++ni)
                bn[ni] = *(const bf16x8*)&Wl[(size_t)((s + 1) * 16 + w_ * 4 + ni) * 512];
        }
        // A-frags: lane l -> row m*16+(l&15), k = s*32 + (l>>4)*8 + j
        bf16x8 a[4];
        #pragma unroll
        for (int m = 0; m < 4; ++m) {
            const int row  = m * 16 + (l & 15);
            const int byte = (row * 512 + s * 64 + ((l >> 4) * 16)) ^ ((l & 7) << 4);
            a[m] = *(const bf16x8*)((const char*)As + byte);
        }
        #pragma unroll
        for (int ni = 0; ni < 4; ++ni)
            #pragma unroll
            for (int m = 0; m < 4; ++m)
                acc[m][ni] = __builtin_amdgcn_mfma_f32_16x16x32_bf16(a[m], bc[ni], acc[m][ni], 0, 0, 0);
        #pragma unroll
        for (int ni = 0; ni < 4; ++ni) bc[ni] = bn[ni];
    }

    // ---- epilogue: h = acc + b1[col]; t = tanh_fast(h); row sums of t*W2 ----
    float part[16];   // [m*4 + r]: node = m*16 + (l>>4)*4 + r, over this wave's 64 cols
    #pragma unroll
    for (int i = 0; i < 16; ++i) part[i] = 0.f;
    #pragma unroll
    for (int ni = 0; ni < 4; ++ni) {
        const int col = w_ * 64 + ni * 16 + (l & 15);
        const float b1c = b1[col];
        const float w2c = W2[col];
        #pragma unroll
        for (int m = 0; m < 4; ++m)
            #pragma unroll
            for (int r = 0; r < 4; ++r)
                part[m * 4 + r] += tanh_fast(acc[m][ni][r] + b1c) * w2c;
    }
    #pragma unroll
    for (int off = 1; off < 16; off <<= 1)
        #pragma unroll
        for (int i = 0; i < 16; ++i)
            part[i] += __shfl_xor(part[i], off, 64);

    if ((l & 15) == 0) {
        const int gq = l >> 4;
        #pragma unroll
        for (int m = 0; m < 4; ++m)
            #pragma unroll
            for (int r = 0; r < 4; ++r)
                epi[w_][m * 16 + gq * 4 + r] = part[m * 4 + r];
    }
    __syncthreads();
    if (tid < 64)
        scores[n0 + tid] = epi[0][tid] + epi[1][tid] + epi[2][tid] + epi[3][tid] + b2[0];
}

// ---------- Kernel 2: per-graph bitonic sort + certain-keep + band extraction ----------
__global__ __launch_bounds__(512)
void k_topk(const float* __restrict__ scores, float* __restrict__ out,
            unsigned int* __restrict__ keep_bits, int* __restrict__ band_idx,
            int* __restrict__ band_n, int* __restrict__ band_lo)
{
    __shared__ float sv[1024];
    __shared__ int   si[1024];
    __shared__ int   s_lo, s_hi;
    const int g = blockIdx.x;
    const int t = threadIdx.x;
    sv[t]       = scores[g * NPG + t];       si[t]       = t;
    sv[t + 512] = scores[g * NPG + t + 512]; si[t + 512] = t + 512;

    for (int size = 2; size <= 1024; size <<= 1) {
        for (int stride = size >> 1; stride > 0; stride >>= 1) {
            __syncthreads();
            const int lo = ((t & ~(stride - 1)) << 1) | (t & (stride - 1));
            const int hi = lo + stride;
            const bool dirDesc = ((lo & size) == 0);
            const float va = sv[lo], vb = sv[hi];
            const int ia = si[lo], ib = si[hi];
            const bool aB = (va > vb) || (va == vb && ia < ib);
            if (aB != dirDesc) {
                sv[lo] = vb; sv[hi] = va;
                si[lo] = ib; si[hi] = ia;
            }
        }
    }
    __syncthreads();
    if (t == 0) { s_hi = 1024; }
    __syncthreads();
    const float tau = sv[511];
    if (sv[t] <= tau + EPS && (t == 0 || sv[t - 1] > tau + EPS)) s_lo = t;
    {
        const int p2 = t + 512;
        if (sv[p2] < tau - EPS && sv[p2 - 1] >= tau - EPS) s_hi = p2;
    }
    __syncthreads();
    const int lo = s_lo;
    const int bn = min(s_hi - lo, CAP);

    const int gi = g * NPG + si[t];
    out[OUT_BATCH + g * KSEL + t] = (float)g;
    if (t < lo) {
        out[OUT_PERM   + g * KSEL + t] = (float)gi;
        out[OUT_SCORES + g * KSEL + t] = sv[t];
        atomicOr(&keep_bits[gi >> 5], 1u << (gi & 31));
    }
    if (t < CAP)
        band_idx[g * CAP + t] = (t < bn) ? si[lo + t] : 0;
    if (t == 0) { band_n[g] = bn; band_lo[g] = lo; }
}

// ---------- Kernel 3: exact fp32 rescore of band nodes ----------
__global__ __launch_bounds__(256, 2)
void k_rescore(const float* __restrict__ x, const float* __restrict__ W1,
               const float* __restrict__ b1, const float* __restrict__ W2,
               const float* __restrict__ b2, const int* __restrict__ band_idx,
               const int* __restrict__ band_n, float* __restrict__ band_scores)
{
    const int g = blockIdx.x >> 2;
    const int c0 = (blockIdx.x & 3) * 32;
    if (band_n[g] <= c0) return;   // uniform early-exit (no barriers crossed)

    __shared__ __align__(16) float W1s[16][CH];
    __shared__ __align__(16) float Xs[32][16];

    const int tid = threadIdx.x;
    const int w_  = tid >> 6;
    const int l   = tid & 63;

    int iv = 0;
    if (w_ < 2) iv = band_idx[g * CAP + c0 + w_ * 16 + (l >> 2)] & 1023;
    const float* xg = x + ((size_t)g * NPG + iv) * CH;

    const float4 b1v = *(const float4*)&b1[l * 4];
    float acc[8][4];
    #pragma unroll
    for (int n = 0; n < 8; ++n) {
        acc[n][0] = b1v.x; acc[n][1] = b1v.y; acc[n][2] = b1v.z; acc[n][3] = b1v.w;
    }

    for (int kc = 0; kc < 16; ++kc) {
        __syncthreads();
        #pragma unroll
        for (int it = 0; it < 4; ++it) {
            const float* gp = W1 + (size_t)kc * (16 * CH) + (w_ * 4 + it) * CH + l * 4;
            float* lb = &W1s[0][0] + (w_ * 4 + it) * CH;
            __builtin_amdgcn_global_load_lds(
                (const __attribute__((address_space(1))) void*)gp,
                (__attribute__((address_space(3))) void*)lb, 16, 0, 0);
        }
        if (w_ < 2) {
            const float* gp = xg + kc * 16 + (l & 3) * 4;
            float* lb = &Xs[0][0] + w_ * 256;
            __builtin_amdgcn_global_load_lds(
                (const __attribute__((address_space(1))) void*)gp,
                (__attribute__((address_space(3))) void*)lb, 16, 0, 0);
        }
        __syncthreads();

        #pragma unroll
        for (int kq = 0; kq < 4; ++kq) {
            const int k4 = kq * 4;
            const float4 wv0 = *(const float4*)&W1s[k4 + 0][l * 4];
            const float4 wv1 = *(const float4*)&W1s[k4 + 1][l * 4];
            const float4 wv2 = *(const float4*)&W1s[k4 + 2][l * 4];
            const float4 wv3 = *(const float4*)&W1s[k4 + 3][l * 4];
            #pragma unroll
            for (int n = 0; n < 8; ++n) {
                const float4 xv = *(const float4*)&Xs[w_ * 8 + n][k4];
                acc[n][0] = fmaf(xv.x, wv0.x, acc[n][0]);
                acc[n][1] = fmaf(xv.x, wv0.y, acc[n][1]);
                acc[n][2] = fmaf(xv.x, wv0.z, acc[n][2]);
                acc[n][3] = fmaf(xv.x, wv0.w, acc[n][3]);
                acc[n][0] = fmaf(xv.y, wv1.x, acc[n][0]);
                acc[n][1] = fmaf(xv.y, wv1.y, acc[n][1]);
                acc[n][2] = fmaf(xv.y, wv1.z, acc[n][2]);
                acc[n][3] = fmaf(xv.y, wv1.w, acc[n][3]);
                acc[n][0] = fmaf(xv.z, wv2.x, acc[n][0]);
                acc[n][1] = fmaf(xv.z, wv2.y, acc[n][1]);
                acc[n][2] = fmaf(xv.z, wv2.z, acc[n][2]);
                acc[n][3] = fmaf(xv.z, wv2.w, acc[n][3]);
                acc[n][0] = fmaf(xv.w, wv3.x, acc[n][0]);
                acc[n][1] = fmaf(xv.w, wv3.y, acc[n][1]);
                acc[n][2] = fmaf(xv.w, wv3.z, acc[n][2]);
                acc[n][3] = fmaf(xv.w, wv3.w, acc[n][3]);
            }
        }
    }

    const float4 w2v = *(const float4*)&W2[l * 4];
    const float  bb  = b2[0];
    float s_[8];
    #pragma unroll
    for (int n = 0; n < 8; ++n) {
        s_[n] = tanhf(acc[n][0]) * w2v.x + tanhf(acc[n][1]) * w2v.y
              + tanhf(acc[n][2]) * w2v.z + tanhf(acc[n][3]) * w2v.w;
    }
    #pragma unroll
    for (int off = 1; off < 64; off <<= 1)
        #pragma unroll
        for (int n = 0; n < 8; ++n)
            s_[n] += __shfl_xor(s_[n], off, 64);

    if (l == 0) {
        #pragma unroll
        for (int n = 0; n < 8; ++n)
            band_scores[g * CAP + c0 + w_ * 8 + n] = s_[n] + bb;
    }
}

// ---------- Kernel 4: select top-(512-lo) of band by fp32 score ----------
__global__ __launch_bounds__(64)
void k_bandsel(const float* __restrict__ band_scores, const int* __restrict__ band_idx,
               const int* __restrict__ band_n, const int* __restrict__ band_lo,
               float* __restrict__ out, unsigned int* __restrict__ keep_bits)
{
    __shared__ float bs[CAP];
    __shared__ int   bi[CAP];
    const int g = blockIdx.x;
    const int t = threadIdx.x;
    const int n  = band_n[g];
    const int lo = band_lo[g];
    int needed = KSEL - lo;
    if (needed > n) needed = n;

    #pragma unroll
    for (int h = 0; h < 2; ++h) {
        const int q = t + h * 64;
        const bool valid = q < n;
        bs[q] = valid ? band_scores[g * CAP + q] : -3.402823466e+38f;
        bi[q] = valid ? band_idx[g * CAP + q] : (NPG + q);
    }
    __syncthreads();
    for (int size = 2; size <= CAP; size <<= 1) {
        for (int stride = size >> 1; stride > 0; stride >>= 1) {
            __syncthreads();
            const int lo_i = ((t & ~(stride - 1)) << 1) | (t & (stride - 1));
            const int hi_i = lo_i + stride;
            const bool dirDesc = ((lo_i & size) == 0);
            const float va = bs[lo_i], vb = bs[hi_i];
            const int ia = bi[lo_i], ib = bi[hi_i];
            const bool aB = (va > vb) || (va == vb && ia < ib);
            if (aB != dirDesc) {
                bs[lo_i] = vb; bs[hi_i] = va;
                bi[lo_i] = ib; bi[hi_i] = ia;
            }
        }
    }
    __syncthreads();
    #pragma unroll
    for (int h = 0; h < 2; ++h) {
        const int s = t + h * 64;
        if (s < needed) {
            const int li = bi[s];
            const int gi = g * NPG + li;
            out[OUT_PERM   + g * KSEL + lo + s] = (float)gi;
            out[OUT_SCORES + g * KSEL + lo + s] = bs[s];
            atomicOr(&keep_bits[gi >> 5], 1u << (gi & 31));
        }
    }
}

// ---------- Kernel 5: gather x_pooled ----------
__global__ __launch_bounds__(256)
void k_gather(const float* __restrict__ x, const float* __restrict__ perm_f,
              float* __restrict__ out_x)
{
    const int row  = blockIdx.x * 4 + (threadIdx.x >> 6);
    const int lane = threadIdx.x & 63;
    const int pi = (int)perm_f[row];
    const float4* src = (const float4*)&x[(size_t)pi * CH];
    float4* dst = (float4*)&out_x[(size_t)row * CH];
    dst[lane] = src[lane];
}

// ---------- Kernel 6: fill edge output with -1 ----------
__global__ __launch_bounds__(256)
void k_fill(float* __restrict__ out_edge)
{
    const int i = blockIdx.x * blockDim.x + threadIdx.x;
    ((float4*)out_edge)[i] = make_float4(-1.f, -1.f, -1.f, -1.f);
}

// ---------- Kernel 7: per-block kept-edge counts ----------
__global__ __launch_bounds__(256)
void k_edgecount(const int* __restrict__ ei, const unsigned int* __restrict__ keep_bits,
                 int* __restrict__ counts)
{
    const int t = threadIdx.x;
    const size_t base = (size_t)blockIdx.x * 4096 + (size_t)t * 16;
    const int* rowp = ei;
    const int* colp = ei + NE;
    int rv[16], cv[16];
    #pragma unroll
    for (int q = 0; q < 4; ++q) {
        int4 r4 = *(const int4*)&rowp[base + q * 4];
        int4 c4 = *(const int4*)&colp[base + q * 4];
        rv[q*4+0]=r4.x; rv[q*4+1]=r4.y; rv[q*4+2]=r4.z; rv[q*4+3]=r4.w;
        cv[q*4+0]=c4.x; cv[q*4+1]=c4.y; cv[q*4+2]=c4.z; cv[q*4+3]=c4.w;
    }
    int cnt = 0;
    #pragma unroll
    for (int q = 0; q < 16; ++q)
        cnt += (int)((keep_bits[rv[q] >> 5] >> (rv[q] & 31)) &
                     (keep_bits[cv[q] >> 5] >> (cv[q] & 31)) & 1u);

    #pragma unroll
    for (int off = 1; off < 64; off <<= 1) cnt += __shfl_xor(cnt, off, 64);
    __shared__ int wsum[4];
    if ((t & 63) == 0) wsum[t >> 6] = cnt;
    __syncthreads();
    if (t == 0) counts[blockIdx.x] = wsum[0] + wsum[1] + wsum[2] + wsum[3];
}

// ---------- Kernel 8: exclusive scan of 1024 block counts ----------
__global__ __launch_bounds__(1024)
void k_scan(const int* __restrict__ counts, int* __restrict__ offsets)
{
    __shared__ int tmp[1024];
    const int t = threadIdx.x;
    const int c = counts[t];
    tmp[t] = c;
    __syncthreads();
    for (int off = 1; off < 1024; off <<= 1) {
        int v = (t >= off) ? tmp[t - off] : 0;
        __syncthreads();
        tmp[t] += v;
        __syncthreads();
    }
    offsets[t] = tmp[t] - c;
}

// ---------- Kernel 9: stable scatter of kept edges ----------
__global__ __launch_bounds__(256)
void k_scatter(const int* __restrict__ ei, const unsigned int* __restrict__ keep_bits,
               const int* __restrict__ offsets, float* __restrict__ out_edge)
{
    const int t = threadIdx.x;
    const size_t base = (size_t)blockIdx.x * 4096 + (size_t)t * 16;
    const int* rowp = ei;
    const int* colp = ei + NE;
    int rv[16], cv[16];
    #pragma unroll
    for (int q = 0; q < 4; ++q) {
        int4 r4 = *(const int4*)&rowp[base + q * 4];
        int4 c4 = *(const int4*)&colp[base + q * 4];
        rv[q*4+0]=r4.x; rv[q*4+1]=r4.y; rv[q*4+2]=r4.z; rv[q*4+3]=r4.w;
        cv[q*4+0]=c4.x; cv[q*4+1]=c4.y; cv[q*4+2]=c4.z; cv[q*4+3]=c4.w;
    }
    unsigned m = 0; int cnt = 0;
    #pragma unroll
    for (int q = 0; q < 16; ++q) {
        const bool kk = ((keep_bits[rv[q] >> 5] >> (rv[q] & 31)) &
                         (keep_bits[cv[q] >> 5] >> (cv[q] & 31)) & 1u) != 0u;
        m |= ((unsigned)kk) << q;
        cnt += (int)kk;
    }
    const int lane = t & 63, w = t >> 6;
    int incl = cnt;
    #pragma unroll
    for (int off = 1; off < 64; off <<= 1) {
        int v = __shfl_up(incl, off, 64);
        if (lane >= off) incl += v;
    }
    __shared__ int wtot[4];
    if (lane == 63) wtot[w] = incl;
    __syncthreads();
    int wbase = 0;
    for (int i = 0; i < w; ++i) wbase += wtot[i];
    int pos = offsets[blockIdx.x] + wbase + (incl - cnt);
    #pragma unroll
    for (int q = 0; q < 16; ++q) {
        if (m & (1u << q)) {
            out_edge[pos]      = (float)rv[q];
            out_edge[NE + pos] = (float)cv[q];
            ++pos;
        }
    }
}

extern "C" void kernel_launch(void* const* d_in, const int* in_sizes, int n_in,
                              void* d_out, int out_size, void* d_ws, size_t ws_size,
                              hipStream_t stream)
{
    const float* x  = (const float*)d_in[0];
    const int*   ei = (const int*)d_in[1];
    const float* W1 = (const float*)d_in[3];
    const float* b1 = (const float*)d_in[4];
    const float* W2 = (const float*)d_in[5];
    const float* b2 = (const float*)d_in[6];

    float* out = (float*)d_out;
    char*  ws  = (char*)d_ws;
    float*          scores    = (float*)(ws + WS_SCORES);
    unsigned int*   keep_bits = (unsigned int*)(ws + WS_KEEP);
    int*            counts    = (int*)(ws + WS_COUNTS);
    int*            offsets   = (int*)(ws + WS_OFFSETS);
    unsigned short* W1b       = (unsigned short*)(ws + WS_BFRAG);
    int*            band_idx  = (int*)(ws + WS_BIDX);
    float*          band_sc   = (float*)(ws + WS_BSCORE);
    int*            band_n    = (int*)(ws + WS_BN);
    int*            band_lo   = (int*)(ws + WS_BLO);

    hipMemsetAsync(keep_bits, 0, NN / 8, stream);

    k_cvtW<<<32, 256, 0, stream>>>(W1, W1b);
    k_mfma_scores<<<NN / 64, 256, 0, stream>>>(x, W1b, b1, W2, b2, scores);
    k_topk<<<NG, 512, 0, stream>>>(scores, out, keep_bits, band_idx, band_n, band_lo);
    k_rescore<<<NG * (CAP / 32), 256, 0, stream>>>(x, W1, b1, W2, b2, band_idx, band_n, band_sc);
    k_bandsel<<<NG, 64, 0, stream>>>(band_sc, band_idx, band_n, band_lo, out, keep_bits);
    k_gather<<<(NG * KSEL) / 4, 256, 0, stream>>>(x, out + OUT_PERM, out + OUT_X);
    k_fill<<<(2 * NE) / (4 * 256), 256, 0, stream>>>(out + OUT_EDGE);
    k_edgecount<<<NE / 4096, 256, 0, stream>>>(ei, keep_bits, counts);
    k_scan<<<1, 1024, 0, stream>>>(counts, offsets);
    k_scatter<<<NE / 4096, 256, 0, stream>>>(ei, keep_bits, offsets, out + OUT_EDGE);
}

// Round 9
// 165.777 us; speedup vs baseline: 2.3006x; 1.0260x over previous
//
#include <hip/hip_runtime.h>
#include <hip/hip_bf16.h>

// Problem constants (static graph layout from the reference)
#define NG 128          // graphs
#define NPG 1024        // nodes per graph
#define NN (NG * NPG)   // 131072 nodes
#define NE (NN * 32)    // 4194304 edges
#define CH 256          // channels
#define KSEL 512        // top-k per graph

#define CAP 128         // band capacity per graph
#define EPS 0.02f       // bf16-score uncertainty band half-width (~100 sigma)

// Output layout (all float32, concatenated flat in return order)
#define OUT_X      0
#define OUT_EDGE   16777216
#define OUT_BATCH  25165824
#define OUT_PERM   25231360
#define OUT_SCORES 25296896

// Workspace layout (bytes)
#define WS_SCORES  0           // 131072 f32
#define WS_KEEP    524288      // bit-packed keep: 16 KB
#define WS_COUNTS  540672      // 1024 int
#define WS_OFFSETS 544768      // 1024 int
#define WS_BFRAG   548864      // W1 bf16 fragment-linear: 128 KB
#define WS_BIDX    679936      // band local idx: NG*CAP int = 64 KB
#define WS_BSCORE  745472      // band fp32 scores: 64 KB
#define WS_BN      811008      // band_n: NG int
#define WS_BLO     811520      // band_lo: NG int

typedef __attribute__((ext_vector_type(8))) short bf16x8;
typedef __attribute__((ext_vector_type(4))) float f32x4;

__device__ __forceinline__ unsigned short f2bf(float f) {
    unsigned int b = __float_as_uint(f);
    return (unsigned short)((b + 0x7fffu + ((b >> 16) & 1u)) >> 16);  // RNE
}

// fast tanh for the APPROX path only: 1 - 2/(exp(2h)+1); saturates, no NaN.
__device__ __forceinline__ float tanh_fast(float h) {
    const float e = __expf(2.0f * h);
    return 1.0f - 2.0f / (e + 1.0f);
}

// ---------- Kernel 0: pack W1 -> bf16 fragment-linear; also zero keep_bits ----------
__global__ __launch_bounds__(256)
void k_cvtW(const float* __restrict__ W1, unsigned short* __restrict__ W1b,
            unsigned int* __restrict__ keep_bits)
{
    const int t = blockIdx.x * 256 + threadIdx.x;   // 0..8191
    if (t < NN / 32) keep_bits[t] = 0u;             // 4096 words
    const int s    = t >> 10;
    const int rem  = t & 1023;
    const int n    = rem >> 6;
    const int lane = rem & 63;
    const int kbase = s * 32 + (lane >> 4) * 8;
    const int col   = n * 16 + (lane & 15);
    unsigned short u[8];
    #pragma unroll
    for (int j = 0; j < 8; ++j)
        u[j] = f2bf(W1[(size_t)(kbase + j) * CH + col]);
    uint4 v;
    v.x = u[0] | ((unsigned int)u[1] << 16);
    v.y = u[2] | ((unsigned int)u[3] << 16);
    v.z = u[4] | ((unsigned int)u[5] << 16);
    v.w = u[6] | ((unsigned int)u[7] << 16);
    *(uint4*)&W1b[(size_t)t * 8] = v;
}

// ---------- Kernel 1: approx scores via bf16 MFMA (v3: chunked async pipeline) ----------
// Block: 256 thr (4 waves), 64 nodes. x staged fp32 in 8 k-chunks of [64][32]
// (8 KB), double-buffered via global_load_lds with PRE-SWIZZLED per-lane source
// (linear LDS dest; phys granule gp holds logical gl = gp ^ (row&7)) so A-frag
// ds_read_b128s are conflict-free. Loop fully unrolled: STAGE(s+1) issued BEFORE
// COMPUTE(s); barrier drain lands ~600 cyc after issue -> HBM latency covered.
// fp32->bf16 conversion in the A-frag build (v_cvt_pk_bf16_f32), RNE == f2bf.
__global__ __launch_bounds__(256, 3)
void k_mfma_scores(const float* __restrict__ x, const unsigned short* __restrict__ W1b,
                   const float* __restrict__ b1, const float* __restrict__ W2,
                   const float* __restrict__ b2, float* __restrict__ scores)
{
    __shared__ __align__(16) float Xf[2][2048];   // 2 x 8 KB fp32 chunks (swizzled granules)
    __shared__ float epi[4][64];

    const int tid = threadIdx.x;
    const int w_  = tid >> 6;
    const int l   = tid & 63;
    const int n0  = blockIdx.x * 64;

    // stage chunk c_ (k in [32c_, 32c_+32)) into buffer b_ (b_, c_ compile-time)
    #define STAGEX(c_, b_)                                                          \
    do {                                                                            \
        _Pragma("unroll")                                                           \
        for (int i = 0; i < 2; ++i) {                                               \
            const int G   = i * 256 + tid;          /* dst granule 0..511 */        \
            const int row = G >> 3;                                                 \
            const int gl  = (G & 7) ^ (row & 7);    /* inverse swizzle on src */    \
            const float* src = x + (size_t)(n0 + row) * CH + (c_) * 32 + gl * 4;    \
            float* lb = &Xf[b_][0] + i * 1024 + w_ * 256;  /* wave-uniform base */  \
            __builtin_amdgcn_global_load_lds(                                       \
                (const __attribute__((address_space(1))) void*)src,                 \
                (__attribute__((address_space(3))) void*)lb, 16, 0, 0);             \
        }                                                                           \
    } while (0)

    f32x4 acc[4][4];
    #pragma unroll
    for (int m = 0; m < 4; ++m)
        #pragma unroll
        for (int n = 0; n < 4; ++n)
            acc[m][n] = (f32x4){0.f, 0.f, 0.f, 0.f};

    // B-frag double buffer (compile-time indices)
    const unsigned short* Wl = W1b + l * 8;
    bf16x8 bc[4], bn[4];
    #pragma unroll
    for (int ni = 0; ni < 4; ++ni)
        bc[ni] = *(const bf16x8*)&Wl[(size_t)(w_ * 4 + ni) * 512];

    STAGEX(0, 0);
    __syncthreads();   // prologue drain of chunk 0

    #pragma unroll
    for (int s = 0; s < 8; ++s) {
        if (s < 7) STAGEX(s + 1, (s + 1) & 1);   // issue next chunk's loads FIRST

        if (s < 7) {
            #pragma unroll
            for (int ni = 0; ni < 4; ++ni)
                bn[ni] = *(const bf16x8*)&Wl[(size_t)((s + 1) * 16 + w_ * 4 + ni) * 512];
        }

        // A-frags from chunk buffer (s&1 is compile-time under full unroll):
        // lane l -> row m*16+(l&15), k_local = (l>>4)*8 + j; granules g0,g0+1
        const char* Xc = (const char*)&Xf[s & 1][0];
        bf16x8 a[4];
        #pragma unroll
        for (int m = 0; m < 4; ++m) {
            const int row = m * 16 + (l & 15);
            const int sw  = row & 7;
            const int g0  = (l >> 4) * 2;
            const float4 f0 = *(const float4*)(Xc + row * 128 + ((g0 ^ sw) << 4));
            const float4 f1 = *(const float4*)(Xc + row * 128 + (((g0 + 1) ^ sw) << 4));
            union { bf16x8 v; __hip_bfloat162 h[4]; } ua;
            ua.h[0] = __float22bfloat162_rn(make_float2(f0.x, f0.y));
            ua.h[1] = __float22bfloat162_rn(make_float2(f0.z, f0.w));
            ua.h[2] = __float22bfloat162_rn(make_float2(f1.x, f1.y));
            ua.h[3] = __float22bfloat162_rn(make_float2(f1.z, f1.w));
            a[m] = ua.v;
        }
        #pragma unroll
        for (int ni = 0; ni < 4; ++ni)
            #pragma unroll
            for (int m = 0; m < 4; ++m)
                acc[m][ni] = __builtin_amdgcn_mfma_f32_16x16x32_bf16(a[m], bc[ni], acc[m][ni], 0, 0, 0);
        #pragma unroll
        for (int ni = 0; ni < 4; ++ni) bc[ni] = bn[ni];

        __syncthreads();   // frees buf[s&1] for STAGE(s+2); drains stage(s+1) with ~600cyc cover
    }
    #undef STAGEX

    // ---- epilogue: h = acc + b1[col]; t = tanh_fast(h); row sums of t*W2 ----
    float part[16];   // [m*4 + r]: node = m*16 + (l>>4)*4 + r
    #pragma unroll
    for (int i = 0; i < 16; ++i) part[i] = 0.f;
    #pragma unroll
    for (int ni = 0; ni < 4; ++ni) {
        const int col = w_ * 64 + ni * 16 + (l & 15);
        const float b1c = b1[col];
        const float w2c = W2[col];
        #pragma unroll
        for (int m = 0; m < 4; ++m)
            #pragma unroll
            for (int r = 0; r < 4; ++r)
                part[m * 4 + r] += tanh_fast(acc[m][ni][r] + b1c) * w2c;
    }
    #pragma unroll
    for (int off = 1; off < 16; off <<= 1)
        #pragma unroll
        for (int i = 0; i < 16; ++i)
            part[i] += __shfl_xor(part[i], off, 64);

    if ((l & 15) == 0) {
        const int gq = l >> 4;
        #pragma unroll
        for (int m = 0; m < 4; ++m)
            #pragma unroll
            for (int r = 0; r < 4; ++r)
                epi[w_][m * 16 + gq * 4 + r] = part[m * 4 + r];
    }
    __syncthreads();
    if (tid < 64)
        scores[n0 + tid] = epi[0][tid] + epi[1][tid] + epi[2][tid] + epi[3][tid] + b2[0];
}

// ---------- Kernel 2: per-graph bitonic sort + certain-keep + band extraction ----------
__global__ __launch_bounds__(512)
void k_topk(const float* __restrict__ scores, float* __restrict__ out,
            unsigned int* __restrict__ keep_bits, int* __restrict__ band_idx,
            int* __restrict__ band_n, int* __restrict__ band_lo)
{
    __shared__ float sv[1024];
    __shared__ int   si[1024];
    __shared__ int   s_lo, s_hi;
    const int g = blockIdx.x;
    const int t = threadIdx.x;
    sv[t]       = scores[g * NPG + t];       si[t]       = t;
    sv[t + 512] = scores[g * NPG + t + 512]; si[t + 512] = t + 512;

    for (int size = 2; size <= 1024; size <<= 1) {
        for (int stride = size >> 1; stride > 0; stride >>= 1) {
            __syncthreads();
            const int lo = ((t & ~(stride - 1)) << 1) | (t & (stride - 1));
            const int hi = lo + stride;
            const bool dirDesc = ((lo & size) == 0);
            const float va = sv[lo], vb = sv[hi];
            const int ia = si[lo], ib = si[hi];
            const bool aB = (va > vb) || (va == vb && ia < ib);
            if (aB != dirDesc) {
                sv[lo] = vb; sv[hi] = va;
                si[lo] = ib; si[hi] = ia;
            }
        }
    }
    __syncthreads();
    if (t == 0) { s_hi = 1024; }
    __syncthreads();
    const float tau = sv[511];
    if (sv[t] <= tau + EPS && (t == 0 || sv[t - 1] > tau + EPS)) s_lo = t;
    {
        const int p2 = t + 512;
        if (sv[p2] < tau - EPS && sv[p2 - 1] >= tau - EPS) s_hi = p2;
    }
    __syncthreads();
    const int lo = s_lo;
    const int bn = min(s_hi - lo, CAP);

    const int gi = g * NPG + si[t];
    out[OUT_BATCH + g * KSEL + t] = (float)g;
    if (t < lo) {
        out[OUT_PERM   + g * KSEL + t] = (float)gi;
        out[OUT_SCORES + g * KSEL + t] = sv[t];
        atomicOr(&keep_bits[gi >> 5], 1u << (gi & 31));
    }
    if (t < CAP)
        band_idx[g * CAP + t] = (t < bn) ? si[lo + t] : 0;
    if (t == 0) { band_n[g] = bn; band_lo[g] = lo; }
}

// ---------- Kernel 3: exact fp32 rescore of band nodes ----------
__global__ __launch_bounds__(256, 2)
void k_rescore(const float* __restrict__ x, const float* __restrict__ W1,
               const float* __restrict__ b1, const float* __restrict__ W2,
               const float* __restrict__ b2, const int* __restrict__ band_idx,
               const int* __restrict__ band_n, float* __restrict__ band_scores)
{
    const int g = blockIdx.x >> 2;
    const int c0 = (blockIdx.x & 3) * 32;
    if (band_n[g] <= c0) return;   // uniform early-exit (no barriers crossed)

    __shared__ __align__(16) float W1s[16][CH];
    __shared__ __align__(16) float Xs[32][16];

    const int tid = threadIdx.x;
    const int w_  = tid >> 6;
    const int l   = tid & 63;

    int iv = 0;
    if (w_ < 2) iv = band_idx[g * CAP + c0 + w_ * 16 + (l >> 2)] & 1023;
    const float* xg = x + ((size_t)g * NPG + iv) * CH;

    const float4 b1v = *(const float4*)&b1[l * 4];
    float acc[8][4];
    #pragma unroll
    for (int n = 0; n < 8; ++n) {
        acc[n][0] = b1v.x; acc[n][1] = b1v.y; acc[n][2] = b1v.z; acc[n][3] = b1v.w;
    }

    for (int kc = 0; kc < 16; ++kc) {
        __syncthreads();
        #pragma unroll
        for (int it = 0; it < 4; ++it) {
            const float* gp = W1 + (size_t)kc * (16 * CH) + (w_ * 4 + it) * CH + l * 4;
            float* lb = &W1s[0][0] + (w_ * 4 + it) * CH;
            __builtin_amdgcn_global_load_lds(
                (const __attribute__((address_space(1))) void*)gp,
                (__attribute__((address_space(3))) void*)lb, 16, 0, 0);
        }
        if (w_ < 2) {
            const float* gp = xg + kc * 16 + (l & 3) * 4;
            float* lb = &Xs[0][0] + w_ * 256;
            __builtin_amdgcn_global_load_lds(
                (const __attribute__((address_space(1))) void*)gp,
                (__attribute__((address_space(3))) void*)lb, 16, 0, 0);
        }
        __syncthreads();

        #pragma unroll
        for (int kq = 0; kq < 4; ++kq) {
            const int k4 = kq * 4;
            const float4 wv0 = *(const float4*)&W1s[k4 + 0][l * 4];
            const float4 wv1 = *(const float4*)&W1s[k4 + 1][l * 4];
            const float4 wv2 = *(const float4*)&W1s[k4 + 2][l * 4];
            const float4 wv3 = *(const float4*)&W1s[k4 + 3][l * 4];
            #pragma unroll
            for (int n = 0; n < 8; ++n) {
                const float4 xv = *(const float4*)&Xs[w_ * 8 + n][k4];
                acc[n][0] = fmaf(xv.x, wv0.x, acc[n][0]);
                acc[n][1] = fmaf(xv.x, wv0.y, acc[n][1]);
                acc[n][2] = fmaf(xv.x, wv0.z, acc[n][2]);
                acc[n][3] = fmaf(xv.x, wv0.w, acc[n][3]);
                acc[n][0] = fmaf(xv.y, wv1.x, acc[n][0]);
                acc[n][1] = fmaf(xv.y, wv1.y, acc[n][1]);
                acc[n][2] = fmaf(xv.y, wv1.z, acc[n][2]);
                acc[n][3] = fmaf(xv.y, wv1.w, acc[n][3]);
                acc[n][0] = fmaf(xv.z, wv2.x, acc[n][0]);
                acc[n][1] = fmaf(xv.z, wv2.y, acc[n][1]);
                acc[n][2] = fmaf(xv.z, wv2.z, acc[n][2]);
                acc[n][3] = fmaf(xv.z, wv2.w, acc[n][3]);
                acc[n][0] = fmaf(xv.w, wv3.x, acc[n][0]);
                acc[n][1] = fmaf(xv.w, wv3.y, acc[n][1]);
                acc[n][2] = fmaf(xv.w, wv3.z, acc[n][2]);
                acc[n][3] = fmaf(xv.w, wv3.w, acc[n][3]);
            }
        }
    }

    const float4 w2v = *(const float4*)&W2[l * 4];
    const float  bb  = b2[0];
    float s_[8];
    #pragma unroll
    for (int n = 0; n < 8; ++n) {
        s_[n] = tanhf(acc[n][0]) * w2v.x + tanhf(acc[n][1]) * w2v.y
              + tanhf(acc[n][2]) * w2v.z + tanhf(acc[n][3]) * w2v.w;
    }
    #pragma unroll
    for (int off = 1; off < 64; off <<= 1)
        #pragma unroll
        for (int n = 0; n < 8; ++n)
            s_[n] += __shfl_xor(s_[n], off, 64);

    if (l == 0) {
        #pragma unroll
        for (int n = 0; n < 8; ++n)
            band_scores[g * CAP + c0 + w_ * 8 + n] = s_[n] + bb;
    }
}

// ---------- Kernel 4: select top-(512-lo) of band by fp32 score ----------
__global__ __launch_bounds__(64)
void k_bandsel(const float* __restrict__ band_scores, const int* __restrict__ band_idx,
               const int* __restrict__ band_n, const int* __restrict__ band_lo,
               float* __restrict__ out, unsigned int* __restrict__ keep_bits)
{
    __shared__ float bs[CAP];
    __shared__ int   bi[CAP];
    const int g = blockIdx.x;
    const int t = threadIdx.x;
    const int n  = band_n[g];
    const int lo = band_lo[g];
    int needed = KSEL - lo;
    if (needed > n) needed = n;

    #pragma unroll
    for (int h = 0; h < 2; ++h) {
        const int q = t + h * 64;
        const bool valid = q < n;
        bs[q] = valid ? band_scores[g * CAP + q] : -3.402823466e+38f;
        bi[q] = valid ? band_idx[g * CAP + q] : (NPG + q);
    }
    __syncthreads();
    for (int size = 2; size <= CAP; size <<= 1) {
        for (int stride = size >> 1; stride > 0; stride >>= 1) {
            __syncthreads();
            const int lo_i = ((t & ~(stride - 1)) << 1) | (t & (stride - 1));
            const int hi_i = lo_i + stride;
            const bool dirDesc = ((lo_i & size) == 0);
            const float va = bs[lo_i], vb = bs[hi_i];
            const int ia = bi[lo_i], ib = bi[hi_i];
            const bool aB = (va > vb) || (va == vb && ia < ib);
            if (aB != dirDesc) {
                bs[lo_i] = vb; bs[hi_i] = va;
                bi[lo_i] = ib; bi[hi_i] = ia;
            }
        }
    }
    __syncthreads();
    #pragma unroll
    for (int h = 0; h < 2; ++h) {
        const int s = t + h * 64;
        if (s < needed) {
            const int li = bi[s];
            const int gi = g * NPG + li;
            out[OUT_PERM   + g * KSEL + lo + s] = (float)gi;
            out[OUT_SCORES + g * KSEL + lo + s] = bs[s];
            atomicOr(&keep_bits[gi >> 5], 1u << (gi & 31));
        }
    }
}

// ---------- Kernel 5: gather x_pooled ----------
__global__ __launch_bounds__(256)
void k_gather(const float* __restrict__ x, const float* __restrict__ perm_f,
              float* __restrict__ out_x)
{
    const int row  = blockIdx.x * 4 + (threadIdx.x >> 6);
    const int lane = threadIdx.x & 63;
    const int pi = (int)perm_f[row];
    const float4* src = (const float4*)&x[(size_t)pi * CH];
    float4* dst = (float4*)&out_x[(size_t)row * CH];
    dst[lane] = src[lane];
}

// ---------- Kernel 6: per-block kept-edge counts + fill our -1 slab ----------
__global__ __launch_bounds__(256)
void k_edgecount(const int* __restrict__ ei, const unsigned int* __restrict__ keep_bits,
                 int* __restrict__ counts, float* __restrict__ out_edge)
{
    const int t = threadIdx.x;
    // fill this block's output slab (4096 edges x 2 halves) with -1
    const float4 neg = make_float4(-1.f, -1.f, -1.f, -1.f);
    #pragma unroll
    for (int q = 0; q < 4; ++q) {
        ((float4*)out_edge)[(size_t)blockIdx.x * 1024 + q * 256 + t] = neg;
        ((float4*)(out_edge + NE))[(size_t)blockIdx.x * 1024 + q * 256 + t] = neg;
    }

    const size_t base = (size_t)blockIdx.x * 4096 + (size_t)t * 16;
    const int* rowp = ei;
    const int* colp = ei + NE;
    int rv[16], cv[16];
    #pragma unroll
    for (int q = 0; q < 4; ++q) {
        int4 r4 = *(const int4*)&rowp[base + q * 4];
        int4 c4 = *(const int4*)&colp[base + q * 4];
        rv[q*4+0]=r4.x; rv[q*4+1]=r4.y; rv[q*4+2]=r4.z; rv[q*4+3]=r4.w;
        cv[q*4+0]=c4.x; cv[q*4+1]=c4.y; cv[q*4+2]=c4.z; cv[q*4+3]=c4.w;
    }
    int cnt = 0;
    #pragma unroll
    for (int q = 0; q < 16; ++q)
        cnt += (int)((keep_bits[rv[q] >> 5] >> (rv[q] & 31)) &
                     (keep_bits[cv[q] >> 5] >> (cv[q] & 31)) & 1u);

    #pragma unroll
    for (int off = 1; off < 64; off <<= 1) cnt += __shfl_xor(cnt, off, 64);
    __shared__ int wsum[4];
    if ((t & 63) == 0) wsum[t >> 6] = cnt;
    __syncthreads();
    if (t == 0) counts[blockIdx.x] = wsum[0] + wsum[1] + wsum[2] + wsum[3];
}

// ---------- Kernel 7: exclusive scan of 1024 block counts ----------
__global__ __launch_bounds__(1024)
void k_scan(const int* __restrict__ counts, int* __restrict__ offsets)
{
    __shared__ int tmp[1024];
    const int t = threadIdx.x;
    const int c = counts[t];
    tmp[t] = c;
    __syncthreads();
    for (int off = 1; off < 1024; off <<= 1) {
        int v = (t >= off) ? tmp[t - off] : 0;
        __syncthreads();
        tmp[t] += v;
        __syncthreads();
    }
    offsets[t] = tmp[t] - c;
}

// ---------- Kernel 8: stable scatter of kept edges ----------
__global__ __launch_bounds__(256)
void k_scatter(const int* __restrict__ ei, const unsigned int* __restrict__ keep_bits,
               const int* __restrict__ offsets, float* __restrict__ out_edge)
{
    const int t = threadIdx.x;
    const size_t base = (size_t)blockIdx.x * 4096 + (size_t)t * 16;
    const int* rowp = ei;
    const int* colp = ei + NE;
    int rv[16], cv[16];
    #pragma unroll
    for (int q = 0; q < 4; ++q) {
        int4 r4 = *(const int4*)&rowp[base + q * 4];
        int4 c4 = *(const int4*)&colp[base + q * 4];
        rv[q*4+0]=r4.x; rv[q*4+1]=r4.y; rv[q*4+2]=r4.z; rv[q*4+3]=r4.w;
        cv[q*4+0]=c4.x; cv[q*4+1]=c4.y; cv[q*4+2]=c4.z; cv[q*4+3]=c4.w;
    }
    unsigned m = 0; int cnt = 0;
    #pragma unroll
    for (int q = 0; q < 16; ++q) {
        const bool kk = ((keep_bits[rv[q] >> 5] >> (rv[q] & 31)) &
                         (keep_bits[cv[q] >> 5] >> (cv[q] & 31)) & 1u) != 0u;
        m |= ((unsigned)kk) << q;
        cnt += (int)kk;
    }
    const int lane = t & 63, w = t >> 6;
    int incl = cnt;
    #pragma unroll
    for (int off = 1; off < 64; off <<= 1) {
        int v = __shfl_up(incl, off, 64);
        if (lane >= off) incl += v;
    }
    __shared__ int wtot[4];
    if (lane == 63) wtot[w] = incl;
    __syncthreads();
    int wbase = 0;
    for (int i = 0; i < w; ++i) wbase += wtot[i];
    int pos = offsets[blockIdx.x] + wbase + (incl - cnt);
    #pragma unroll
    for (int q = 0; q < 16; ++q) {
        if (m & (1u << q)) {
            out_edge[pos]      = (float)rv[q];
            out_edge[NE + pos] = (float)cv[q];
            ++pos;
        }
    }
}

extern "C" void kernel_launch(void* const* d_in, const int* in_sizes, int n_in,
                              void* d_out, int out_size, void* d_ws, size_t ws_size,
                              hipStream_t stream)
{
    const float* x  = (const float*)d_in[0];
    const int*   ei = (const int*)d_in[1];
    const float* W1 = (const float*)d_in[3];
    const float* b1 = (const float*)d_in[4];
    const float* W2 = (const float*)d_in[5];
    const float* b2 = (const float*)d_in[6];

    float* out = (float*)d_out;
    char*  ws  = (char*)d_ws;
    float*          scores    = (float*)(ws + WS_SCORES);
    unsigned int*   keep_bits = (unsigned int*)(ws + WS_KEEP);
    int*            counts    = (int*)(ws + WS_COUNTS);
    int*            offsets   = (int*)(ws + WS_OFFSETS);
    unsigned short* W1b       = (unsigned short*)(ws + WS_BFRAG);
    int*            band_idx  = (int*)(ws + WS_BIDX);
    float*          band_sc   = (float*)(ws + WS_BSCORE);
    int*            band_n    = (int*)(ws + WS_BN);
    int*            band_lo   = (int*)(ws + WS_BLO);

    k_cvtW<<<32, 256, 0, stream>>>(W1, W1b, keep_bits);
    k_mfma_scores<<<NN / 64, 256, 0, stream>>>(x, W1b, b1, W2, b2, scores);
    k_topk<<<NG, 512, 0, stream>>>(scores, out, keep_bits, band_idx, band_n, band_lo);
    k_rescore<<<NG * (CAP / 32), 256, 0, stream>>>(x, W1, b1, W2, b2, band_idx, band_n, band_sc);
    k_bandsel<<<NG, 64, 0, stream>>>(band_sc, band_idx, band_n, band_lo, out, keep_bits);
    k_gather<<<(NG * KSEL) / 4, 256, 0, stream>>>(x, out + OUT_PERM, out + OUT_X);
    k_edgecount<<<NE / 4096, 256, 0, stream>>>(ei, keep_bits, counts, out + OUT_EDGE);
    k_scan<<<1, 1024, 0, stream>>>(counts, offsets);
    k_scatter<<<NE / 4096, 256, 0, stream>>>(ei, keep_bits, offsets, out + OUT_EDGE);
}